// Round 15
// baseline (3198.203 us; speedup 1.0000x reference)
//
#include <hip/hip_runtime.h>
#include <math.h>

typedef double f64;
#define HDIM 64
#define NNODES 1024
#define NROWS 2048
#define RPB 4              // rows per block (block-shared across waves)
#define NTHR 256           // 4 waves; wave w owns j-quarter w, all 4 rows
#define NBLK (NROWS/RPB)   // 512 blocks -> 2 blocks/CU

__device__ __forceinline__ f64 wredsum64(f64 v){
#pragma unroll
  for(int o=32;o>0;o>>=1) v += __shfl_xor(v,o);
  return v;
}

// two-stage score, same op-order as the absmax-0 lineage
__device__ __forceinline__ void s_twostage64(const f64* ldsrow,
    const float* __restrict__ g_tr_w, const float* __restrict__ g_tr_b,
    const float* __restrict__ g_a, int h, f64& s_src, f64& s_dst){
  f64 t = (f64)g_tr_b[h];
  for(int c=0;c<HDIM;c++) t = fma(ldsrow[c], (f64)g_tr_w[c*HDIM+h], t);
  s_src = wredsum64(t*(f64)g_a[h]);
  s_dst = wredsum64(t*(f64)g_a[HDIM+h]);
}

// initial h1 + scores (1 wave/row) + folded f64 weight transpose
__global__ void k1(const float* __restrict__ x, const float* __restrict__ fw,
                   const float* __restrict__ fb,
                   const float* __restrict__ g_in_w, const float* __restrict__ g_in_b,
                   const float* __restrict__ g_tr_w, const float* __restrict__ g_tr_b,
                   const float* __restrict__ g_a,
                   const float* __restrict__ w_ih, const float* __restrict__ w_hh,
                   f64* __restrict__ w_ihT, f64* __restrict__ w_hhT,
                   f64* __restrict__ h1, f64* __restrict__ ssrc, f64* __restrict__ sdst){
  __shared__ f64 lx[4*64];
  __shared__ f64 lt[4*64];
  int wave = threadIdx.x >> 6, h = threadIdx.x & 63;
  int kk = blockIdx.x*256 + threadIdx.x;
  if(kk < 192*HDIM){
    int row=kk>>6, c=kk&63;
    w_ihT[c*192+row]=(f64)w_ih[kk];
    w_hhT[c*192+row]=(f64)w_hh[kk];
  }
  int r = blockIdx.x*4 + wave;
  int b = r >> 10, n = r & 1023;
  const float* xp = x + ((long)(b*32 + 0)*1024 + n)*6;
  f64 xh = (f64)fb[h];
#pragma unroll
  for(int f=0;f<6;f++) xh += (f64)xp[f]*(f64)fw[f*HDIM+h];
  lx[wave*64+h] = xh;
  __syncthreads();
  f64 a = (f64)g_in_b[h];
  for(int c=0;c<HDIM;c++) a += lx[wave*64+c]*(f64)g_in_w[c*HDIM+h];
  h1[(long)r*HDIM+h] = a;
  lt[wave*64+h] = a;
  __syncthreads();
  f64 s1,s2;
  s_twostage64(lt+wave*64, g_tr_w,g_tr_b,g_a, h, s1,s2);
  if(h==0){ ssrc[r]=s1; sdst[r]=s2; }
}

// One full GAT iteration per dispatch. 512 blocks x 256 thr.
// Wave w: j-quarter w (256 j, as 16 tiles of 16 j, rotated start), ALL 4 rows
// (4 accumulators/lane -> 4 FMA per LDS data read). Wave-private LDS tile,
// NO block barriers in the agg loop. Quarter partials combined via LDS at end.
// M=0: h1_out = agg + residual, + scores. M=1: GRU; next-h1+scores | FFN.
template<int M>
__global__ __launch_bounds__(NTHR) void k_att(
    const f64* __restrict__ h1_in, const f64* __restrict__ ss_in,
    const f64* __restrict__ sd_in,
    f64* __restrict__ h1_out, f64* __restrict__ ss_out, f64* __restrict__ sd_out,
    const float* __restrict__ g_tr_w, const float* __restrict__ g_tr_b,
    const float* __restrict__ g_a,
    const float* __restrict__ x, const float* __restrict__ fw, const float* __restrict__ fb,
    const f64* __restrict__ w_ihT, const f64* __restrict__ w_hhT,
    const float* __restrict__ b_ih, const float* __restrict__ b_hh,
    const float* __restrict__ g_in_w, const float* __restrict__ g_in_b,
    const float* __restrict__ ffn_w, const float* __restrict__ ffn_b,
    const float* __restrict__ ffn_ow, const float* __restrict__ ffn_ob,
    float* __restrict__ out, int step, int is_final)
{
  // pool: [0..4095] 4x wave tile (16jx64h each, 8KB) ; [4096..4351] 4x wrow(64)
  // after agg loop (re-aliased): pacS [0..1023] = [q][r][h]; pws [1024..1039];
  // lrow [1088..1343]; lx [1344..1599]; lh [1600..1855]
  __shared__ __align__(16) f64 pool[4096 + 256];
  __shared__ f64 lds_m[RPB], lds_sd[RPB];
  __shared__ f64 red[4];

  const int tid = threadIdx.x, wave = tid>>6, h = tid&63;
  const int bid = blockIdx.x;
  const int batch = bid>>8;              // 256 blocks per batch
  const int nloc = (bid&255)*RPB;
  const long gr0 = (long)batch*NNODES + nloc;
  const int y = wave;                    // tail row for this wave
  const long gry = gr0 + y;

  // batch max of s_src (exact row max via monotonicity; max is order-exact)
  const f64* sb = ss_in + (long)batch*NNODES;
  f64 mx = -1e300;
  for(int j=tid;j<NNODES;j+=NTHR) mx = fmax(mx, sb[j]);
#pragma unroll
  for(int o=32;o>0;o>>=1) mx = fmax(mx, __shfl_xor(mx,o));
  if(h==0) red[wave]=mx;
  __syncthreads();
  f64 maxS = fmax(fmax(red[0],red[1]),fmax(red[2],red[3]));
  if(tid<RPB){
    f64 sd = sd_in[gr0+tid];
    lds_sd[tid]=sd;
    f64 v = maxS + sd;
    lds_m[tid] = (v>=0.0)? v : 0.01*v;
  }
  __syncthreads();

  f64 acc0=0.0, acc1=0.0, acc2=0.0, acc3=0.0;  // rows 0..3, this wave's quarter
  f64 wsk=0.0;                                 // lane partial: row h>>4

  const f64* hbase = h1_in + (long)batch*NNODES*HDIM;
  const int t0 = bid & 15;                     // tile rotation within quarter
  f64* wt = pool + wave*1024;                  // wave tile: [16 j][64 h]
  f64* wr = pool + 4096 + wave*64;             // wave weights: [4 rows][16 jj]
  const int wrow_r = h >> 4, wjj = h & 15;     // this lane's (row,jj) for weights

  for(int k=0;k<16;k++){
    const int t = (t0 + k) & 15;
    const int j0 = wave*256 + t*16;
    // stage 16x64 f64 (8KB): 8 double2/lane, coalesced
    const double2* src = (const double2*)(hbase + (long)j0*HDIM);
#pragma unroll
    for(int q=0;q<8;q++) ((double2*)wt)[h + q*64] = src[h + q*64];
    // weights: lane -> (row=h>>4, jj=h&15); exact per-element op order
    {
      f64 v = sb[j0 + wjj] + lds_sd[wrow_r];
      v = (v>=0.0)? v : 0.01*v;
      f64 e = exp(v - lds_m[wrow_r]);
      wr[h] = e;           // wr[row*16+jj] == wr[h]
      wsk += e;
    }
    __threadfence_block();  // wave-sync: staging + weight LDS writes visible
    // FMA: 4 rows share each data read
#pragma unroll
    for(int p=0;p<8;p++){
      f64 d0 = wt[(2*p)*64 + h];
      f64 d1 = wt[(2*p+1)*64 + h];
      double2 w0 = *(const double2*)(wr      + 2*p);
      double2 w1 = *(const double2*)(wr + 16 + 2*p);
      double2 w2 = *(const double2*)(wr + 32 + 2*p);
      double2 w3 = *(const double2*)(wr + 48 + 2*p);
      acc0 = fma(w0.x,d0,acc0); acc0 = fma(w0.y,d1,acc0);
      acc1 = fma(w1.x,d0,acc1); acc1 = fma(w1.y,d1,acc1);
      acc2 = fma(w2.x,d0,acc2); acc2 = fma(w2.y,d1,acc2);
      acc3 = fma(w3.x,d0,acc3); acc3 = fma(w3.y,d1,acc3);
    }
  }
  // ws: reduce lane partials within 16-lane (jj) groups -> row sums per quarter
#pragma unroll
  for(int o=1;o<16;o<<=1) wsk += __shfl_xor(wsk, o);
  __syncthreads();   // waves done with tiles; re-alias pool
  // write quarter partials: pacS[(q*4+r)*64+h], pws pool[1024+q*4+r]
  pool[(wave*4+0)*64+h]=acc0;
  pool[(wave*4+1)*64+h]=acc1;
  pool[(wave*4+2)*64+h]=acc2;
  pool[(wave*4+3)*64+h]=acc3;
  if(wjj==0) pool[1024 + wave*4 + wrow_r] = wsk;
  __syncthreads();
  // combine (fixed order q0->q3); wave w owns row y=w
  f64 a = pool[(0*4+y)*64+h];
  a += pool[(1*4+y)*64+h];
  a += pool[(2*4+y)*64+h];
  a += pool[(3*4+y)*64+h];
  f64 wsum = pool[1024+0*4+y];
  wsum += pool[1024+1*4+y];
  wsum += pool[1024+2*4+y];
  wsum += pool[1024+3*4+y];
  f64 outv = a/wsum + h1_in[gry*HDIM + h];

  f64* lrow = pool + 1088;
  f64* lx   = pool + 1344;
  f64* lh   = pool + 1600;

  if(M==0){
    h1_out[gry*HDIM+h]=outv;
    lrow[y*64+h]=outv;
    __syncthreads();
    f64 s1,s2;
    s_twostage64(lrow+y*64, g_tr_w,g_tr_b,g_a, h, s1,s2);
    if(h==0){ ss_out[gry]=s1; sd_out[gry]=s2; }
  } else {
    lrow[y*64+h]=outv;
    const bool hasxi = (step>0);
    if(hasxi){
      const float* xp = x + ((long)(batch*32+step)*1024 + nloc+y)*6;
      f64 xa = (f64)fb[h];
#pragma unroll
      for(int f=0;f<6;f++) xa += (f64)xp[f]*(f64)fw[f*HDIM+h];
      lx[y*64+h]=xa;
    }
    __syncthreads();
    // GRU (same c-order as absmax-0 lineage)
    {
      f64 gi0=(f64)b_ih[h], gi1=(f64)b_ih[64+h], gi2=(f64)b_ih[128+h];
      f64 gh0=(f64)b_hh[h], gh1=(f64)b_hh[64+h], gh2=(f64)b_hh[128+h];
      for(int c=0;c<HDIM;c++){
        f64 o = lrow[y*64+c];
        f64 in = hasxi ? lx[y*64+c] : o;
        gi0 += in*w_ihT[c*192+h]; gi1 += in*w_ihT[c*192+64+h]; gi2 += in*w_ihT[c*192+128+h];
        if(hasxi){
          gh0 += o*w_hhT[c*192+h]; gh1 += o*w_hhT[c*192+64+h]; gh2 += o*w_hhT[c*192+128+h];
        }
      }
      f64 rr = 1.0/(1.0+exp(-(gi0+gh0)));
      f64 zz = 1.0/(1.0+exp(-(gi1+gh1)));
      f64 nn = tanh(gi2 + rr*gh2);
      f64 hn = hasxi ? ((1.0-zz)*nn + zz*outv) : (1.0-zz)*nn;
      lh[y*64+h] = hn;
    }
    __syncthreads();
    if(!is_final){
      f64 a1 = (f64)g_in_b[h];
      for(int c=0;c<HDIM;c++) a1 += lh[y*64+c]*(f64)g_in_w[c*HDIM+h];
      h1_out[gry*HDIM+h]=a1;
      lx[y*64+h]=a1;
      __syncthreads();
      f64 s1,s2;
      s_twostage64(lx+y*64, g_tr_w,g_tr_b,g_a, h, s1,s2);
      if(h==0){ ss_out[gry]=s1; sd_out[gry]=s2; }
    } else {
      f64 hid = (f64)ffn_b[h];
      for(int c=0;c<HDIM;c++) hid += lh[y*64+c]*(f64)ffn_w[c*HDIM+h];
      hid = (hid>=0.0)? hid : 0.01*hid;
      f64 o2 = wredsum64(hid*(f64)ffn_ow[h]);
      if(h==0) out[gry] = (float)(o2 + (f64)ffn_ob[0]);
    }
  }
}

extern "C" void kernel_launch(void* const* d_in, const int* in_sizes, int n_in,
                              void* d_out, int out_size, void* d_ws, size_t ws_size,
                              hipStream_t stream){
  const float* x      = (const float*)d_in[0];
  const float* fc_in_w= (const float*)d_in[1];
  const float* fc_in_b= (const float*)d_in[2];
  const float* g_in_w = (const float*)d_in[3];
  const float* g_in_b = (const float*)d_in[4];
  const float* g_tr_w = (const float*)d_in[5];
  const float* g_tr_b = (const float*)d_in[6];
  const float* g_a    = (const float*)d_in[7];
  const float* w_ih   = (const float*)d_in[8];
  const float* w_hh   = (const float*)d_in[9];
  const float* b_ih   = (const float*)d_in[10];
  const float* b_hh   = (const float*)d_in[11];
  const float* ffn_w  = (const float*)d_in[12];
  const float* ffn_b  = (const float*)d_in[13];
  const float* ffn_ow = (const float*)d_in[14];
  const float* ffn_ob = (const float*)d_in[15];

  f64* h1a   = (f64*)d_ws;
  f64* h1b   = h1a + (long)NROWS*HDIM;
  f64* ssa   = h1b + (long)NROWS*HDIM;
  f64* sda   = ssa + NROWS;
  f64* ssb   = sda + NROWS;
  f64* sdb   = ssb + NROWS;
  f64* w_ihT = sdb + NROWS;
  f64* w_hhT = w_ihT + 192*HDIM;

  float* dout = (float*)d_out;

  k1<<<NROWS/4,256,0,stream>>>(x, fc_in_w, fc_in_b, g_in_w,g_in_b,
                               g_tr_w,g_tr_b,g_a, w_ih,w_hh, w_ihT,w_hhT,
                               h1a,ssa,sda);

  for(int s=0;s<31;s++){
    k_att<0><<<NBLK,NTHR,0,stream>>>(h1a,ssa,sda, h1b,ssb,sdb,
                                     g_tr_w,g_tr_b,g_a,
                                     x,fc_in_w,fc_in_b,
                                     w_ihT,w_hhT,b_ih,b_hh,
                                     g_in_w,g_in_b,
                                     ffn_w,ffn_b,ffn_ow,ffn_ob,
                                     dout, s, 0);
    k_att<1><<<NBLK,NTHR,0,stream>>>(h1b,ssb,sdb, h1a,ssa,sda,
                                     g_tr_w,g_tr_b,g_a,
                                     x,fc_in_w,fc_in_b,
                                     w_ihT,w_hhT,b_ih,b_hh,
                                     g_in_w,g_in_b,
                                     ffn_w,ffn_b,ffn_ow,ffn_ob,
                                     dout, s, (s==30)?1:0);
  }
}